// Round 14
// baseline (583.926 us; speedup 1.0000x reference)
//
#include <hip/hip_runtime.h>
#include <hip/hip_bf16.h>

// Clockwork RNN, hierarchical decomposition + bf16 MFMA GEMMs.
// Round 14: k_phase v9 — barrier-free wave-private scan.
//   wave 0 (compute): A in VGPRs (32 frags), h in private 16-slot LDS ring
//     (same-wave DS in order => no barriers per step), u via own gld_lds
//     8-slot ring with uniform counted vmcnt(32). All in-loop DS = inline asm.
//   wave 1 (storer): drains h-ring pages of 8 steps to hmod, 1 barrier/page.
// k_xw / k_u / k_out unchanged from R13.

#define TT 256
#define BB 128
#define INW 512
#define HH 128
#define MHW 1024

typedef __bf16 bf16x8 __attribute__((ext_vector_type(8)));
typedef __bf16 bf16x4 __attribute__((ext_vector_type(4)));
typedef float f32x4 __attribute__((ext_vector_type(4)));
typedef unsigned int u32x2 __attribute__((ext_vector_type(2)));
typedef __attribute__((address_space(3))) char lds_char;

__constant__ unsigned int c_hmod_off[8] = {
    0u, 4194304u, 6291456u, 7340032u, 7864320u, 8126464u, 8257536u, 8323072u};

__device__ __forceinline__ int active_thr(int t) {
    int ma = (t == 0) ? 8 : min(__ffs(t), 8);
    return ma * HH;
}

__device__ __forceinline__ unsigned short f2bf(float f) {
    union { float f; unsigned int u; } v{f};
    unsigned int r = v.u + 0x7FFFu + ((v.u >> 16) & 1u);  // RNE
    return (unsigned short)(r >> 16);
}
__device__ __forceinline__ unsigned int pack2(float lo, float hi) {
    return (unsigned int)f2bf(lo) | ((unsigned int)f2bf(hi) << 16);
}
__device__ __forceinline__ float bf2f(unsigned short u) {
    union { unsigned int i; float f; } v;
    v.i = ((unsigned int)u) << 16;
    return v.f;
}

__device__ __forceinline__ void gld_lds16(const void* g, char* l) {
    __builtin_amdgcn_global_load_lds(
        (const __attribute__((address_space(1))) void*)g,
        (__attribute__((address_space(3))) void*)l, 16, 0, 0);
}

// inline-asm DS ops (invisible to compiler waitcnt tracking; rule #18 fences
// are applied at call sites via lgkmcnt + sched_barrier)
__device__ __forceinline__ f32x4 ds_read128_f(const lds_char* p) {
    f32x4 r;
    asm volatile("ds_read_b128 %0, %1" : "=v"(r) : "v"(p));
    return r;
}
__device__ __forceinline__ bf16x8 ds_read128_h(const lds_char* p) {
    bf16x8 r;
    asm volatile("ds_read_b128 %0, %1" : "=v"(r) : "v"(p));
    return r;
}
__device__ __forceinline__ void ds_write64(lds_char* p, u32x2 v) {
    asm volatile("ds_write_b64 %0, %1" ::"v"(p), "v"(v) : "memory");
}

// Read one 16x32 bf16 fragment (8 bf16) from a swizzled bf16 tile.
__device__ __forceinline__ bf16x8 frag_ld(const char* tile, int row, int ks, int lane) {
    int off = (row * 128 + ks * 64 + (lane >> 4) * 16) ^ ((row & 7) << 4);
    return *reinterpret_cast<const bf16x8*>(tile + off);
}

// Read one fragment from a swizzled *f32* tile ([rows][64] f32, 256B/row),
// convert to bf16x8.
__device__ __forceinline__ bf16x8 frag_ld_f32(const char* tile, int row, int ks, int g) {
    int off = ((row << 8) + ks * 128 + g * 32) ^ ((row & 7) << 4);
    f32x4 a = *reinterpret_cast<const f32x4*>(tile + off);
    f32x4 b = *reinterpret_cast<const f32x4*>(tile + (off ^ 16));
    bf16x8 u;
    u[0] = (__bf16)a[0]; u[1] = (__bf16)a[1]; u[2] = (__bf16)a[2]; u[3] = (__bf16)a[3];
    u[4] = (__bf16)b[0]; u[5] = (__bf16)b[1]; u[6] = (__bf16)b[2]; u[7] = (__bf16)b[3];
    return u;
}

// ---------------------------------------------------------------------------
// K_xw (unchanged R13): 1020 uniform blocks, gld_lds f32 staging.
// ---------------------------------------------------------------------------
__global__ __launch_bounds__(256) void k_xw(const float* __restrict__ x,
                                            const float* __restrict__ Wxh,
                                            const float* __restrict__ bh,
                                            float* __restrict__ xwb) {
    __shared__ char ldsW[2][32768];
    __shared__ char ldsX[2][16384];
    int id = blockIdx.x >> 1, half = blockIdx.x & 1;
    int rt = 0, rem = id;
    while (rem >= (256 >> rt)) { rem -= 256 >> rt; ++rt; }
    int t = rem << rt;

    int tid = threadIdx.x, lane = tid & 63, wid = tid >> 6;
    int l15 = lane & 15, g = lane >> 4;
    int wr = (wid >> 1) * 64, wc = (wid & 1) * 32;

    const float* gW[8];
    const float* gX[4];
    {
        int kb = (lane & 15) * 16;
#pragma unroll
        for (int i = 0; i < 8; ++i) {
            int row = i * 16 + wid * 4 + (lane >> 4);
            int kf = (kb ^ ((row & 7) << 4)) >> 2;
            gW[i] = Wxh + (size_t)(rt * 128 + row) * INW + kf;
        }
#pragma unroll
        for (int i = 0; i < 4; ++i) {
            int row = i * 16 + wid * 4 + (lane >> 4);
            int kf = (kb ^ ((row & 7) << 4)) >> 2;
            gX[i] = x + ((size_t)t * BB + half * 64 + row) * INW + kf;
        }
    }
#pragma unroll
    for (int i = 0; i < 8; ++i)
        gld_lds16(gW[i], &ldsW[0][0] + i * 4096 + wid * 1024);
#pragma unroll
    for (int i = 0; i < 4; ++i)
        gld_lds16(gX[i], &ldsX[0][0] + i * 4096 + wid * 1024);

    f32x4 acc[4][2] = {};
    for (int c = 0; c < 8; ++c) {
        int cur = c & 1;
        __syncthreads();
        if (c < 7) {
#pragma unroll
            for (int i = 0; i < 8; ++i)
                gld_lds16(gW[i] + (c + 1) * 64,
                          &ldsW[cur ^ 1][0] + i * 4096 + wid * 1024);
#pragma unroll
            for (int i = 0; i < 4; ++i)
                gld_lds16(gX[i] + (c + 1) * 64,
                          &ldsX[cur ^ 1][0] + i * 4096 + wid * 1024);
        }
#pragma unroll
        for (int ks = 0; ks < 2; ++ks) {
            bf16x8 fa[4], fb[2];
#pragma unroll
            for (int i = 0; i < 4; ++i)
                fa[i] = frag_ld_f32(&ldsW[cur][0], wr + i * 16 + l15, ks, g);
#pragma unroll
            for (int j = 0; j < 2; ++j)
                fb[j] = frag_ld_f32(&ldsX[cur][0], wc + j * 16 + l15, ks, g);
#pragma unroll
            for (int i = 0; i < 4; ++i)
#pragma unroll
                for (int j = 0; j < 2; ++j)
                    acc[i][j] = __builtin_amdgcn_mfma_f32_16x16x32_bf16(
                        fa[i], fb[j], acc[i][j], 0, 0, 0);
        }
    }
#pragma unroll
    for (int i = 0; i < 4; ++i) {
        int rbase = rt * 128 + wr + i * 16 + g * 4;
        float4 bias = *reinterpret_cast<const float4*>(&bh[rbase]);
#pragma unroll
        for (int j = 0; j < 2; ++j) {
            int b = half * 64 + wc + j * 16 + l15;
            float4 v = make_float4(acc[i][j][0] + bias.x, acc[i][j][1] + bias.y,
                                   acc[i][j][2] + bias.z, acc[i][j][3] + bias.w);
            *reinterpret_cast<float4*>(
                &xwb[(size_t)(t * BB + b) * MHW + rbase]) = v;
        }
    }
}

// ---------------------------------------------------------------------------
// K_u (unchanged R13): gld_lds staging for A (f32) and H (hprev f32 / hmod bf16).
// ---------------------------------------------------------------------------
__global__ __launch_bounds__(256) void k_u(const float* __restrict__ Whh,
                                           const float* __restrict__ hprev,
                                           const unsigned short* __restrict__ hmod,
                                           float* __restrict__ xwb, int mi) {
    __shared__ char lds[131072];
    char* ldsA0 = lds;
    char* ldsA1 = lds + 32768;
    char* ldsH0 = lds + 65536;
    char* ldsH1 = lds + 98304;
    int k = blockIdx.x;
    int t = k << mi;
    int tid = threadIdx.x, lane = tid & 63, wid = tid >> 6;
    int l15 = lane & 15, g = lane >> 4;
    int wr = (wid >> 1) * 64, wc = (wid & 1) * 64;
    int ntile = 2 * (7 - mi);

    const float* gA[8];
    {
        int kb = l15 * 16;
#pragma unroll
        for (int i = 0; i < 8; ++i) {
            int row = i * 16 + wid * 4 + g;
            int kf = (kb ^ ((row & 7) << 4)) >> 2;
            gA[i] = Whh + (size_t)(mi * HH + row) * MHW + kf;
        }
    }
    f32x4 acc[4][4] = {};

    if (k == 0) {
        const float* gH[8];
        {
            int kb = l15 * 16;
#pragma unroll
            for (int i = 0; i < 8; ++i) {
                int row = i * 16 + wid * 4 + g;
                int kf = (kb ^ ((row & 7) << 4)) >> 2;
                gH[i] = hprev + (size_t)row * MHW + kf;
            }
        }
        auto stage = [&](int tt, char* dA, char* dH) {
            int j = mi + 1 + (tt >> 1), c0 = (tt & 1) * 64;
            int off = j * HH + c0;
#pragma unroll
            for (int i = 0; i < 8; ++i)
                gld_lds16(gA[i] + off, dA + i * 4096 + wid * 1024);
#pragma unroll
            for (int i = 0; i < 8; ++i)
                gld_lds16(gH[i] + off, dH + i * 4096 + wid * 1024);
        };
        stage(0, ldsA0, ldsH0);
        for (int tt = 0; tt < ntile; ++tt) {
            int cur = tt & 1;
            __syncthreads();
            if (tt + 1 < ntile)
                stage(tt + 1, cur ? ldsA0 : ldsA1, cur ? ldsH0 : ldsH1);
            const char* sA = cur ? ldsA1 : ldsA0;
            const char* sH = cur ? ldsH1 : ldsH0;
#pragma unroll
            for (int ks = 0; ks < 2; ++ks) {
                bf16x8 fa[4], fb[4];
#pragma unroll
                for (int i = 0; i < 4; ++i) {
                    fa[i] = frag_ld_f32(sA, wr + i * 16 + l15, ks, g);
                    fb[i] = frag_ld_f32(sH, wc + i * 16 + l15, ks, g);
                }
#pragma unroll
                for (int i = 0; i < 4; ++i)
#pragma unroll
                    for (int jj = 0; jj < 4; ++jj)
                        acc[i][jj] = __builtin_amdgcn_mfma_f32_16x16x32_bf16(
                            fa[i], fb[jj], acc[i][jj], 0, 0, 0);
            }
        }
    } else {
        size_t hoff[4];
        {
            int cb = ((lane & 7) * 16) ^ ((lane >> 3) << 4);
#pragma unroll
            for (int p = 0; p < 4; ++p) {
                int row = p * 32 + wid * 8 + (lane >> 3);
                hoff[p] = (size_t)row * HH + (cb >> 1);
            }
        }
        auto stage = [&](int tt, char* dA, char* dH) {
            int j = mi + 1 + (tt >> 1), c0 = (tt & 1) * 64;
            int offA = j * HH + c0;
#pragma unroll
            for (int i = 0; i < 8; ++i)
                gld_lds16(gA[i] + offA, dA + i * 4096 + wid * 1024);
            const unsigned short* hb =
                hmod + c_hmod_off[j] + (size_t)((t - 1) >> j) * BB * HH + c0;
#pragma unroll
            for (int p = 0; p < 4; ++p)
                gld_lds16(hb + hoff[p], dH + p * 4096 + wid * 1024);
        };
        stage(0, ldsA0, ldsH0);
        for (int tt = 0; tt < ntile; ++tt) {
            int cur = tt & 1;
            __syncthreads();
            if (tt + 1 < ntile)
                stage(tt + 1, cur ? ldsA0 : ldsA1, cur ? ldsH0 : ldsH1);
            const char* sA = cur ? ldsA1 : ldsA0;
            const char* sH = cur ? ldsH1 : ldsH0;
#pragma unroll
            for (int ks = 0; ks < 2; ++ks) {
                bf16x8 fa[4], fb[4];
#pragma unroll
                for (int i = 0; i < 4; ++i) {
                    fa[i] = frag_ld_f32(sA, wr + i * 16 + l15, ks, g);
                    fb[i] = frag_ld(sH, wc + i * 16 + l15, ks, lane);
                }
#pragma unroll
                for (int i = 0; i < 4; ++i)
#pragma unroll
                    for (int jj = 0; jj < 4; ++jj)
                        acc[i][jj] = __builtin_amdgcn_mfma_f32_16x16x32_bf16(
                            fa[i], fb[jj], acc[i][jj], 0, 0, 0);
            }
        }
    }
#pragma unroll
    for (int i = 0; i < 4; ++i) {
        int rbase = wr + i * 16 + g * 4;
#pragma unroll
        for (int j = 0; j < 4; ++j) {
            int b = wc + j * 16 + l15;
            float4* p = reinterpret_cast<float4*>(
                &xwb[(size_t)(t * BB + b) * MHW + mi * HH + rbase]);
            float4 v = *p;
            v.x += acc[i][j][0]; v.y += acc[i][j][1];
            v.z += acc[i][j][2]; v.w += acc[i][j][3];
            *p = v;
        }
    }
}

// ---------------------------------------------------------------------------
// K_phase v9: barrier-free wave-private scan.
// grid 8 blocks x 16 batches, 128 thr = wave 0 compute, wave 1 storer.
// ---------------------------------------------------------------------------
#define SYNC_LDS()                                              \
    do {                                                        \
        asm volatile("s_waitcnt lgkmcnt(0)" ::: "memory");      \
        __builtin_amdgcn_sched_barrier(0);                      \
        __builtin_amdgcn_s_barrier();                           \
        __builtin_amdgcn_sched_barrier(0);                      \
    } while (0)

__global__ __launch_bounds__(128) void k_phase(const float* __restrict__ Whh,
                                               const float* __restrict__ hprev,
                                               const float* __restrict__ xwb,
                                               unsigned short* __restrict__ hmod,
                                               int mi) {
    int b0 = blockIdx.x * 16;
    int tid = threadIdx.x, lane = tid & 63, wid = tid >> 6;
    int l15 = lane & 15, g = lane >> 4;
    __shared__ char ring[16 * 4096];  // h ring, slot K&15: [b][r] bf16 swizzled
    __shared__ char sU[8][8192];      // u ring, slot K&7: [r/4][b] f32, linear
    int Tm = TT >> mi;
    int P = min(8, Tm);

    if (wid == 0) {
        // ================= compute wave =================
        bf16x8 Af[8][4];
        {
            const float* Ab = Whh + (size_t)(mi * HH) * MHW + mi * HH;
#pragma unroll
            for (int m = 0; m < 8; ++m) {
                const float* row = Ab + (size_t)(m * 16 + l15) * MHW;
#pragma unroll
                for (int kf = 0; kf < 4; ++kf) {
                    float4 v0 = *reinterpret_cast<const float4*>(row + kf * 32 + g * 8);
                    float4 v1 = *reinterpret_cast<const float4*>(row + kf * 32 + g * 8 + 4);
                    bf16x8 u;
                    u[0] = (__bf16)v0.x; u[1] = (__bf16)v0.y;
                    u[2] = (__bf16)v0.z; u[3] = (__bf16)v0.w;
                    u[4] = (__bf16)v1.x; u[5] = (__bf16)v1.y;
                    u[6] = (__bf16)v1.z; u[7] = (__bf16)v1.w;
                    Af[m][kf] = u;
                }
            }
        }
        int roff[4], woff[8], uoff[8];
#pragma unroll
        for (int kf = 0; kf < 4; ++kf)
            roff[kf] = (l15 * 256 + kf * 64 + g * 16) ^ ((l15 & 7) << 4);
#pragma unroll
        for (int m = 0; m < 8; ++m) {
            woff[m] = (l15 * 256 + (m * 16 + g * 4) * 2) ^ ((l15 & 7) << 4);
            uoff[m] = (4 * m + g) * 256 + l15 * 16;
        }
        lds_char* ring3 = (lds_char*)&ring[0];
        lds_char* su3 = (lds_char*)&sU[0][0];

        // h_{-1} -> ring slot 15 (own-wave DS writes; in-order w.r.t. reads)
        {
            const float* hp = hprev + (size_t)(b0 + l15) * MHW + mi * HH;
#pragma unroll
            for (int m = 0; m < 8; ++m) {
                float4 v = *reinterpret_cast<const float4*>(hp + m * 16 + g * 4);
                u32x2 pk;
                pk[0] = pack2(v.x, v.y);
                pk[1] = pack2(v.z, v.w);
                ds_write64(ring3 + 15 * 4096 + woff[m], pk);
            }
        }
        // u prologue: slots 0..3
        const float* ubase = xwb + (size_t)(b0 + l15) * MHW + mi * HH + g * 4;
#pragma unroll
        for (int q = 0; q < 4; ++q) {
            int t = min(q, Tm - 1) << mi;
            const float* pt = ubase + (size_t)t * BB * MHW;
#pragma unroll
            for (int p = 0; p < 8; ++p)
                gld_lds16(pt + p * 16, &sU[q][0] + p * 1024);
        }

        for (int page = 0; page < Tm; page += P) {
#pragma unroll 1
            for (int s = 0; s < P; ++s) {
                int K = page + s;
                {  // prefetch u slot K+4
                    int t = min(K + 4, Tm - 1) << mi;
                    int slot = (K + 4) & 7;
                    const float* pt = ubase + (size_t)t * BB * MHW;
#pragma unroll
                    for (int p = 0; p < 8; ++p)
                        gld_lds16(pt + p * 16, &sU[slot][0] + p * 1024);
                }
                // slot K landed: exactly 32 loads (slots K+1..K+4) are newer
                asm volatile("s_waitcnt vmcnt(32)" ::: "memory");
                __builtin_amdgcn_sched_barrier(0);

                const lds_char* ub = su3 + (K & 7) * 8192;
                const lds_char* hin = ring3 + ((K + 15) & 15) * 4096;
                lds_char* hout = ring3 + (K & 15) * 4096;

                f32x4 acc[8];
#pragma unroll
                for (int m = 0; m < 8; ++m)
                    acc[m] = ds_read128_f(ub + uoff[m]);
                bf16x8 Bf[4];
#pragma unroll
                for (int kf = 0; kf < 4; ++kf)
                    Bf[kf] = ds_read128_h(hin + roff[kf]);
                asm volatile("s_waitcnt lgkmcnt(0)" ::: "memory");
                __builtin_amdgcn_sched_barrier(0);

#pragma unroll
                for (int kf = 0; kf < 4; ++kf)
#pragma unroll
                    for (int m = 0; m < 8; ++m)
                        acc[m] = __builtin_amdgcn_mfma_f32_16x16x32_bf16(
                            Af[m][kf], Bf[kf], acc[m], 0, 0, 0);
#pragma unroll
                for (int m = 0; m < 8; ++m) {
                    u32x2 pk;
                    pk[0] = pack2(acc[m][0], acc[m][1]);
                    pk[1] = pack2(acc[m][2], acc[m][3]);
                    ds_write64(hout + woff[m], pk);
                }
            }
            SYNC_LDS();  // page complete; storer may drain it
        }
        asm volatile("s_waitcnt vmcnt(0) lgkmcnt(0)" ::: "memory");
    } else {
        // ================= storer wave =================
        int bq = lane >> 2;
        int rr = (lane & 3) * 32;
        unsigned short* hm = hmod + c_hmod_off[mi] + (size_t)(b0 + bq) * HH + rr;
        int soff[4];
#pragma unroll
        for (int c = 0; c < 4; ++c)
            soff[c] = (bq * 256 + (rr + c * 8) * 2) ^ ((bq & 7) << 4);
        for (int page = 0; page < Tm; page += P) {
            SYNC_LDS();  // wait for compute to finish this page
#pragma unroll 1
            for (int s = 0; s < P; ++s) {
                int K = page + s;
                const char* slot = &ring[(K & 15) * 4096];
                uint4 h[4];
#pragma unroll
                for (int c = 0; c < 4; ++c)
                    h[c] = *reinterpret_cast<const uint4*>(slot + soff[c]);
                unsigned short* dst = hm + (size_t)K * BB * HH;
#pragma unroll
                for (int c = 0; c < 4; ++c)
                    *reinterpret_cast<uint4*>(dst + c * 8) = h[c];
            }
        }
    }
}

// ---------------------------------------------------------------------------
// K_out (unchanged): out[t][b][j*H + h] = bf2f(Hmod[j][t>>j][b][h]); h_last.
// ---------------------------------------------------------------------------
__global__ __launch_bounds__(256) void k_out(const unsigned short* __restrict__ hmod,
                                             float* __restrict__ out) {
    int b = blockIdx.x, t = blockIdx.y;
    int tid = threadIdx.x;
    int i = tid * 4;
    int j = i >> 7;
    int k = t >> j;
    ushort4 h = *reinterpret_cast<const ushort4*>(
        &hmod[c_hmod_off[j] + ((size_t)k * BB + b) * HH + (i & 127)]);
    float4 v = make_float4(bf2f(h.x), bf2f(h.y), bf2f(h.z), bf2f(h.w));
    *reinterpret_cast<float4*>(&out[((size_t)t * BB + b) * MHW + i]) = v;
    if (t == TT - 1) {
        *reinterpret_cast<float4*>(
            &out[(size_t)TT * BB * MHW + (size_t)b * MHW + i]) = v;
    }
}

// ---------------------------------------------------------------------------
extern "C" void kernel_launch(void* const* d_in, const int* in_sizes, int n_in,
                              void* d_out, int out_size, void* d_ws, size_t ws_size,
                              hipStream_t stream) {
    const float* x = (const float*)d_in[0];
    const float* hprev = (const float*)d_in[1];
    const float* Wxh = (const float*)d_in[2];
    const float* Whh = (const float*)d_in[3];
    const float* bh = (const float*)d_in[4];
    float* out = (float*)d_out;

    float* xwb = out;                              // scratch in d_out
    unsigned short* hmod = (unsigned short*)d_ws;  // bf16, 16.7 MB

    k_xw<<<dim3(1020), 256, 0, stream>>>(x, Wxh, bh, xwb);

    for (int mi = 7; mi >= 0; --mi) {
        if (mi < 7)
            k_u<<<dim3(TT >> mi), 256, 0, stream>>>(Whh, hprev, hmod, xwb, mi);
        k_phase<<<8, 128, 0, stream>>>(Whh, hprev, xwb, hmod, mi);
    }

    k_out<<<dim3(128, 256), 256, 0, stream>>>(hmod, out);
}

// Round 15
// 506.724 us; speedup vs baseline: 1.1524x; 1.1524x over previous
//
#include <hip/hip_runtime.h>
#include <hip/hip_bf16.h>

// Clockwork RNN. Round 15: fused persistent kernel.
//   k_xw (1020 blocks, unchanged + flag zeroing) -> k_mega (256 blocks) -> k_out.
//   k_mega: blocks 0-7 = scan blocks (R13 v6 wave-specialized phase, loop mi=7..0);
//           blocks 8-255 = workers running 508 k_u items via atomic work queue.
//   Flags (agent-scope atomics in d_ws): uflag[7][256] worker->scan,
//   hpage[8][32] scan->worker (8-slot pages, ==8 when all scan blocks wrote).
//   Scan storer wave pre-verifies u-flags one step ahead so the producer
//   wave's counted vmcnt(24) pipeline never executes polls.

#define TT 256
#define BB 128
#define INW 512
#define HH 128
#define MHW 1024

typedef __bf16 bf16x8 __attribute__((ext_vector_type(8)));
typedef __bf16 bf16x4 __attribute__((ext_vector_type(4)));
typedef float f32x4 __attribute__((ext_vector_type(4)));

__constant__ unsigned int c_hmod_off[8] = {
    0u, 4194304u, 6291456u, 7340032u, 7864320u, 8126464u, 8257536u, 8323072u};

__device__ __forceinline__ unsigned short f2bf(float f) {
    union { float f; unsigned int u; } v{f};
    unsigned int r = v.u + 0x7FFFu + ((v.u >> 16) & 1u);  // RNE
    return (unsigned short)(r >> 16);
}
__device__ __forceinline__ unsigned int pack2(float lo, float hi) {
    return (unsigned int)f2bf(lo) | ((unsigned int)f2bf(hi) << 16);
}
__device__ __forceinline__ float bf2f(unsigned short u) {
    union { unsigned int i; float f; } v;
    v.i = ((unsigned int)u) << 16;
    return v.f;
}

__device__ __forceinline__ void gld_lds16(const void* g, char* l) {
    __builtin_amdgcn_global_load_lds(
        (const __attribute__((address_space(1))) void*)g,
        (__attribute__((address_space(3))) void*)l, 16, 0, 0);
}

__device__ __forceinline__ unsigned int aload(unsigned int* p) {
    return __hip_atomic_load(p, __ATOMIC_RELAXED, __HIP_MEMORY_SCOPE_AGENT);
}
__device__ __forceinline__ void aadd(unsigned int* p, unsigned int v) {
    __hip_atomic_fetch_add(p, v, __ATOMIC_RELAXED, __HIP_MEMORY_SCOPE_AGENT);
}

// Read one 16x32 bf16 fragment from a swizzled bf16 tile ([rows][64] bf16).
__device__ __forceinline__ bf16x8 frag_ld(const char* tile, int row, int ks, int lane) {
    int off = (row * 128 + ks * 64 + (lane >> 4) * 16) ^ ((row & 7) << 4);
    return *reinterpret_cast<const bf16x8*>(tile + off);
}

// Read one fragment from a swizzled f32 tile ([rows][64] f32), cvt to bf16x8.
__device__ __forceinline__ bf16x8 frag_ld_f32(const char* tile, int row, int ks, int g) {
    int off = ((row << 8) + ks * 128 + g * 32) ^ ((row & 7) << 4);
    f32x4 a = *reinterpret_cast<const f32x4*>(tile + off);
    f32x4 b = *reinterpret_cast<const f32x4*>(tile + (off ^ 16));
    bf16x8 u;
    u[0] = (__bf16)a[0]; u[1] = (__bf16)a[1]; u[2] = (__bf16)a[2]; u[3] = (__bf16)a[3];
    u[4] = (__bf16)b[0]; u[5] = (__bf16)b[1]; u[6] = (__bf16)b[2]; u[7] = (__bf16)b[3];
    return u;
}

// ---------------------------------------------------------------------------
// K_xw (R13 + flag zeroing in block 0).
// ---------------------------------------------------------------------------
__global__ __launch_bounds__(256) void k_xw(const float* __restrict__ x,
                                            const float* __restrict__ Wxh,
                                            const float* __restrict__ bh,
                                            float* __restrict__ xwb,
                                            unsigned int* __restrict__ flags) {
    __shared__ char ldsW[2][32768];
    __shared__ char ldsX[2][16384];
    int tid = threadIdx.x;
    if (blockIdx.x == 0) {
        for (int i = tid; i < 2052; i += 256) flags[i] = 0u;
    }
    int id = blockIdx.x >> 1, half = blockIdx.x & 1;
    int rt = 0, rem = id;
    while (rem >= (256 >> rt)) { rem -= 256 >> rt; ++rt; }
    int t = rem << rt;

    int lane = tid & 63, wid = tid >> 6;
    int l15 = lane & 15, g = lane >> 4;
    int wr = (wid >> 1) * 64, wc = (wid & 1) * 32;

    const float* gW[8];
    const float* gX[4];
    {
        int kb = (lane & 15) * 16;
#pragma unroll
        for (int i = 0; i < 8; ++i) {
            int row = i * 16 + wid * 4 + (lane >> 4);
            int kf = (kb ^ ((row & 7) << 4)) >> 2;
            gW[i] = Wxh + (size_t)(rt * 128 + row) * INW + kf;
        }
#pragma unroll
        for (int i = 0; i < 4; ++i) {
            int row = i * 16 + wid * 4 + (lane >> 4);
            int kf = (kb ^ ((row & 7) << 4)) >> 2;
            gX[i] = x + ((size_t)t * BB + half * 64 + row) * INW + kf;
        }
    }
#pragma unroll
    for (int i = 0; i < 8; ++i)
        gld_lds16(gW[i], &ldsW[0][0] + i * 4096 + wid * 1024);
#pragma unroll
    for (int i = 0; i < 4; ++i)
        gld_lds16(gX[i], &ldsX[0][0] + i * 4096 + wid * 1024);

    f32x4 acc[4][2] = {};
    for (int c = 0; c < 8; ++c) {
        int cur = c & 1;
        __syncthreads();
        if (c < 7) {
#pragma unroll
            for (int i = 0; i < 8; ++i)
                gld_lds16(gW[i] + (c + 1) * 64,
                          &ldsW[cur ^ 1][0] + i * 4096 + wid * 1024);
#pragma unroll
            for (int i = 0; i < 4; ++i)
                gld_lds16(gX[i] + (c + 1) * 64,
                          &ldsX[cur ^ 1][0] + i * 4096 + wid * 1024);
        }
#pragma unroll
        for (int ks = 0; ks < 2; ++ks) {
            bf16x8 fa[4], fb[2];
#pragma unroll
            for (int i = 0; i < 4; ++i)
                fa[i] = frag_ld_f32(&ldsW[cur][0], wr + i * 16 + l15, ks, g);
#pragma unroll
            for (int j = 0; j < 2; ++j)
                fb[j] = frag_ld_f32(&ldsX[cur][0], wc + j * 16 + l15, ks, g);
#pragma unroll
            for (int i = 0; i < 4; ++i)
#pragma unroll
                for (int j = 0; j < 2; ++j)
                    acc[i][j] = __builtin_amdgcn_mfma_f32_16x16x32_bf16(
                        fa[i], fb[j], acc[i][j], 0, 0, 0);
        }
    }
#pragma unroll
    for (int i = 0; i < 4; ++i) {
        int rbase = rt * 128 + wr + i * 16 + g * 4;
        float4 bias = *reinterpret_cast<const float4*>(&bh[rbase]);
#pragma unroll
        for (int j = 0; j < 2; ++j) {
            int b = half * 64 + wc + j * 16 + l15;
            float4 v = make_float4(acc[i][j][0] + bias.x, acc[i][j][1] + bias.y,
                                   acc[i][j][2] + bias.z, acc[i][j][3] + bias.w);
            *reinterpret_cast<float4*>(
                &xwb[(size_t)(t * BB + b) * MHW + rbase]) = v;
        }
    }
}

// ---------------------------------------------------------------------------
// u_body: R13 k_u body as a device function (worker role).
// ---------------------------------------------------------------------------
__device__ void u_body(int mi, int k, const float* __restrict__ Whh,
                       const float* __restrict__ hprev,
                       const unsigned short* __restrict__ hmod,
                       float* __restrict__ xwb, char* lds) {
    char* ldsA0 = lds;
    char* ldsA1 = lds + 32768;
    char* ldsH0 = lds + 65536;
    char* ldsH1 = lds + 98304;
    int t = k << mi;
    int tid = threadIdx.x, lane = tid & 63, wid = tid >> 6;
    int l15 = lane & 15, g = lane >> 4;
    int wr = (wid >> 1) * 64, wc = (wid & 1) * 64;
    int ntile = 2 * (7 - mi);

    const float* gA[8];
    {
        int kb = l15 * 16;
#pragma unroll
        for (int i = 0; i < 8; ++i) {
            int row = i * 16 + wid * 4 + g;
            int kf = (kb ^ ((row & 7) << 4)) >> 2;
            gA[i] = Whh + (size_t)(mi * HH + row) * MHW + kf;
        }
    }
    f32x4 acc[4][4] = {};

    if (k == 0) {
        const float* gH[8];
        {
            int kb = l15 * 16;
#pragma unroll
            for (int i = 0; i < 8; ++i) {
                int row = i * 16 + wid * 4 + g;
                int kf = (kb ^ ((row & 7) << 4)) >> 2;
                gH[i] = hprev + (size_t)row * MHW + kf;
            }
        }
        auto stage = [&](int tt, char* dA, char* dH) {
            int j = mi + 1 + (tt >> 1), c0 = (tt & 1) * 64;
            int off = j * HH + c0;
#pragma unroll
            for (int i = 0; i < 8; ++i)
                gld_lds16(gA[i] + off, dA + i * 4096 + wid * 1024);
#pragma unroll
            for (int i = 0; i < 8; ++i)
                gld_lds16(gH[i] + off, dH + i * 4096 + wid * 1024);
        };
        stage(0, ldsA0, ldsH0);
        for (int tt = 0; tt < ntile; ++tt) {
            int cur = tt & 1;
            __syncthreads();
            if (tt + 1 < ntile)
                stage(tt + 1, cur ? ldsA0 : ldsA1, cur ? ldsH0 : ldsH1);
            const char* sA = cur ? ldsA1 : ldsA0;
            const char* sH = cur ? ldsH1 : ldsH0;
#pragma unroll
            for (int ks = 0; ks < 2; ++ks) {
                bf16x8 fa[4], fb[4];
#pragma unroll
                for (int i = 0; i < 4; ++i) {
                    fa[i] = frag_ld_f32(sA, wr + i * 16 + l15, ks, g);
                    fb[i] = frag_ld_f32(sH, wc + i * 16 + l15, ks, g);
                }
#pragma unroll
                for (int i = 0; i < 4; ++i)
#pragma unroll
                    for (int jj = 0; jj < 4; ++jj)
                        acc[i][jj] = __builtin_amdgcn_mfma_f32_16x16x32_bf16(
                            fa[i], fb[jj], acc[i][jj], 0, 0, 0);
            }
        }
    } else {
        size_t hoff[4];
        {
            int cb = ((lane & 7) * 16) ^ ((lane >> 3) << 4);
#pragma unroll
            for (int p = 0; p < 4; ++p) {
                int row = p * 32 + wid * 8 + (lane >> 3);
                hoff[p] = (size_t)row * HH + (cb >> 1);
            }
        }
        auto stage = [&](int tt, char* dA, char* dH) {
            int j = mi + 1 + (tt >> 1), c0 = (tt & 1) * 64;
            int offA = j * HH + c0;
#pragma unroll
            for (int i = 0; i < 8; ++i)
                gld_lds16(gA[i] + offA, dA + i * 4096 + wid * 1024);
            const unsigned short* hb =
                hmod + c_hmod_off[j] + (size_t)((t - 1) >> j) * BB * HH + c0;
#pragma unroll
            for (int p = 0; p < 4; ++p)
                gld_lds16(hb + hoff[p], dH + p * 4096 + wid * 1024);
        };
        stage(0, ldsA0, ldsH0);
        for (int tt = 0; tt < ntile; ++tt) {
            int cur = tt & 1;
            __syncthreads();
            if (tt + 1 < ntile)
                stage(tt + 1, cur ? ldsA0 : ldsA1, cur ? ldsH0 : ldsH1);
            const char* sA = cur ? ldsA1 : ldsA0;
            const char* sH = cur ? ldsH1 : ldsH0;
#pragma unroll
            for (int ks = 0; ks < 2; ++ks) {
                bf16x8 fa[4], fb[4];
#pragma unroll
                for (int i = 0; i < 4; ++i) {
                    fa[i] = frag_ld_f32(sA, wr + i * 16 + l15, ks, g);
                    fb[i] = frag_ld(sH, wc + i * 16 + l15, ks, lane);
                }
#pragma unroll
                for (int i = 0; i < 4; ++i)
#pragma unroll
                    for (int jj = 0; jj < 4; ++jj)
                        acc[i][jj] = __builtin_amdgcn_mfma_f32_16x16x32_bf16(
                            fa[i], fb[jj], acc[i][jj], 0, 0, 0);
            }
        }
    }
#pragma unroll
    for (int i = 0; i < 4; ++i) {
        int rbase = wr + i * 16 + g * 4;
#pragma unroll
        for (int j = 0; j < 4; ++j) {
            int b = wc + j * 16 + l15;
            float4* p = reinterpret_cast<float4*>(
                &xwb[(size_t)(t * BB + b) * MHW + mi * HH + rbase]);
            float4 v = *p;
            v.x += acc[i][j][0]; v.y += acc[i][j][1];
            v.z += acc[i][j][2]; v.w += acc[i][j][3];
            *p = v;
        }
    }
}

// ---------------------------------------------------------------------------
// K_mega: 256 blocks. Blocks 0-7 scan (v6 per phase, mi=7..0); 8-255 workers.
// ---------------------------------------------------------------------------
#define SYNC_LDS()                                              \
    do {                                                        \
        asm volatile("s_waitcnt lgkmcnt(0)" ::: "memory");      \
        __builtin_amdgcn_sched_barrier(0);                      \
        __builtin_amdgcn_s_barrier();                           \
        __builtin_amdgcn_sched_barrier(0);                      \
    } while (0)
#define SYNC_VM24()                                             \
    do {                                                        \
        asm volatile("s_waitcnt vmcnt(24)" ::: "memory");       \
        __builtin_amdgcn_sched_barrier(0);                      \
        __builtin_amdgcn_s_barrier();                           \
        __builtin_amdgcn_sched_barrier(0);                      \
    } while (0)

__device__ __forceinline__ void item_of(int i, int& mi, int& k) {
    if (i < 4) { mi = 6; k = i; }
    else if (i < 12) { mi = 5; k = i - 4; }
    else if (i < 28) { mi = 4; k = i - 12; }
    else if (i < 60) { mi = 3; k = i - 28; }
    else if (i < 124) { mi = 2; k = i - 60; }
    else if (i < 252) { mi = 1; k = i - 124; }
    else { mi = 0; k = i - 252; }
}

__global__ __launch_bounds__(256) void k_mega(const float* __restrict__ Whh,
                                              const float* __restrict__ hprev,
                                              float* __restrict__ xwb,
                                              unsigned short* __restrict__ hmod,
                                              unsigned int* __restrict__ flags) {
    __shared__ char smem[131072];
    __shared__ int s_item;
    unsigned int* uflag = flags;          // [7][256]
    unsigned int* hpage = flags + 1792;   // [8][32]
    unsigned int* counter = flags + 2048;
    int tid = threadIdx.x, lane = tid & 63, wid = tid >> 6;
    int l15 = lane & 15, g = lane >> 4;

    if (blockIdx.x < 8) {
        // ===================== scan block =====================
        int b0 = blockIdx.x * 16;
        char* sH0 = smem;                 // sH[2][4096]
        char* sU0 = smem + 8192;          // sU[8][8192]

        int roff[4], woff4[4], uoff4[4], soff[4];
#pragma unroll
        for (int kf = 0; kf < 4; ++kf)
            roff[kf] = (l15 * 256 + kf * 64 + g * 16) ^ ((l15 & 7) << 4);
#pragma unroll
        for (int mm = 0; mm < 4; ++mm) {
            woff4[mm] = (l15 * 256 + (64 * (wid & 1) + mm * 16 + g * 4) * 2) ^ ((l15 & 7) << 4);
            uoff4[mm] = (16 * (wid & 1) + 4 * mm + g) * 256 + l15 * 16;
        }
        {
            int bq = lane >> 2, rr = (lane & 3) * 32;
#pragma unroll
            for (int c = 0; c < 4; ++c)
                soff[c] = (bq * 256 + (rr + c * 8) * 2) ^ ((bq & 7) << 4);
        }

        for (int mi = 7; mi >= 0; --mi) {
            int Tm = TT >> mi;
            if (wid < 2) {
                // ---- compute waves ----
                bf16x8 Af[4][4];
                {
                    const float* Ab = Whh + (size_t)(mi * HH) * MHW + mi * HH;
#pragma unroll
                    for (int mm = 0; mm < 4; ++mm) {
                        const float* row = Ab + (size_t)(64 * wid + mm * 16 + l15) * MHW;
#pragma unroll
                        for (int kf = 0; kf < 4; ++kf) {
                            float4 v0 = *reinterpret_cast<const float4*>(row + kf * 32 + g * 8);
                            float4 v1 = *reinterpret_cast<const float4*>(row + kf * 32 + g * 8 + 4);
                            bf16x8 u;
                            u[0] = (__bf16)v0.x; u[1] = (__bf16)v0.y;
                            u[2] = (__bf16)v0.z; u[3] = (__bf16)v0.w;
                            u[4] = (__bf16)v1.x; u[5] = (__bf16)v1.y;
                            u[6] = (__bf16)v1.z; u[7] = (__bf16)v1.w;
                            Af[mm][kf] = u;
                        }
                    }
                }
#pragma unroll
                for (int p = 0; p < 2; ++p) {
                    int tt = tid + p * 128;
                    int b = tt >> 4, r8 = (tt & 15) * 8;
                    const float* hp = hprev + (size_t)(b0 + b) * MHW + mi * HH + r8;
                    float4 v0 = *reinterpret_cast<const float4*>(hp);
                    float4 v1 = *reinterpret_cast<const float4*>(hp + 4);
                    uint4 pk;
                    pk.x = pack2(v0.x, v0.y); pk.y = pack2(v0.z, v0.w);
                    pk.z = pack2(v1.x, v1.y); pk.w = pack2(v1.z, v1.w);
                    int off = (b * 256 + r8 * 2) ^ ((b & 7) << 4);
                    *reinterpret_cast<uint4*>(sH0 + off) = pk;
                }
                SYNC_LDS();
                for (int K = 0; K < Tm; ++K) {
                    int cur = K & 1;
                    const char* ub = sU0 + (K & 7) * 8192;
                    f32x4 acc[4], acc2[4];
#pragma unroll
                    for (int mm = 0; mm < 4; ++mm) {
                        acc[mm] = *reinterpret_cast<const f32x4*>(ub + uoff4[mm]);
                        acc2[mm] = (f32x4){0.f, 0.f, 0.f, 0.f};
                    }
                    bf16x8 Bf[4];
#pragma unroll
                    for (int kf = 0; kf < 4; ++kf)
                        Bf[kf] = *reinterpret_cast<const bf16x8*>(sH0 + cur * 4096 + roff[kf]);
#pragma unroll
                    for (int mm = 0; mm < 4; ++mm) {
                        acc[mm] = __builtin_amdgcn_mfma_f32_16x16x32_bf16(
                            Af[mm][0], Bf[0], acc[mm], 0, 0, 0);
                        acc2[mm] = __builtin_amdgcn_mfma_f32_16x16x32_bf16(
                            Af[mm][2], Bf[2], acc2[mm], 0, 0, 0);
                        acc[mm] = __builtin_amdgcn_mfma_f32_16x16x32_bf16(
                            Af[mm][1], Bf[1], acc[mm], 0, 0, 0);
                        acc2[mm] = __builtin_amdgcn_mfma_f32_16x16x32_bf16(
                            Af[mm][3], Bf[3], acc2[mm], 0, 0, 0);
                    }
#pragma unroll
                    for (int mm = 0; mm < 4; ++mm) {
                        acc[mm] += acc2[mm];
                        bf16x4 pk;
                        pk[0] = (__bf16)acc[mm][0]; pk[1] = (__bf16)acc[mm][1];
                        pk[2] = (__bf16)acc[mm][2]; pk[3] = (__bf16)acc[mm][3];
                        *reinterpret_cast<bf16x4*>(sH0 + (cur ^ 1) * 4096 + woff4[mm]) = pk;
                    }
                    SYNC_LDS();
                }
                SYNC_LDS();  // phase end
            } else if (wid == 2) {
                // ---- u producer ----
                const float* ubase = xwb + (size_t)(b0 + l15) * MHW + mi * HH + g * 4;
                if (mi < 7) {  // prologue flags (pre-gld_lds: vmcnt pollution harmless)
                    int pmax = min(3, Tm - 1);
                    for (int q = 0; q <= pmax; ++q)
                        while (aload(&uflag[mi * 256 + q]) == 0u)
                            __builtin_amdgcn_s_sleep(16);
                }
#pragma unroll
                for (int q = 0; q < 4; ++q) {
                    int t = min(q, Tm - 1) << mi;
                    const float* pt = ubase + (size_t)t * BB * MHW;
#pragma unroll
                    for (int p = 0; p < 8; ++p)
                        gld_lds16(pt + p * 16, sU0 + q * 8192 + p * 1024);
                }
                SYNC_VM24();
                for (int K = 0; K < Tm; ++K) {
                    int t = min(K + 4, Tm - 1) << mi;
                    int slot = (K + 4) & 7;
                    const float* pt = ubase + (size_t)t * BB * MHW;
#pragma unroll
                    for (int p = 0; p < 8; ++p)
                        gld_lds16(pt + p * 16, sU0 + slot * 8192 + p * 1024);
                    SYNC_VM24();
                }
                asm volatile("s_waitcnt vmcnt(0)" ::: "memory");
                SYNC_LDS();  // phase end
            } else {
                // ---- h storer (+ u-flag verification one step ahead) ----
                int bq = lane >> 2;
                int rr = (lane & 3) * 32;
                unsigned short* hm = hmod + c_hmod_off[mi] + (size_t)(b0 + bq) * HH + rr;
                int verified = (mi < 7) ? -1 : (1 << 30);
                auto verify = [&](int target) {
                    while (verified < target) {
                        if (aload(&uflag[mi * 256 + verified + 1]) != 0u) ++verified;
                        else __builtin_amdgcn_s_sleep(16);
                    }
                };
                if (mi < 7) verify(min(4, Tm - 1));
                SYNC_LDS();
                for (int K = 0; K < Tm; ++K) {
                    if (mi < 7) verify(min(K + 5, Tm - 1));
                    if (K >= 1) {
                        int s = K - 1;
                        uint4 h[4];
#pragma unroll
                        for (int c = 0; c < 4; ++c)
                            h[c] = *reinterpret_cast<const uint4*>(
                                smem + (K & 1) * 4096 + soff[c]);
                        unsigned short* dst = hm + (size_t)s * BB * HH;
#pragma unroll
                        for (int c = 0; c < 4; ++c)
                            *reinterpret_cast<uint4*>(dst + c * 8) = h[c];
                        if (mi > 0 && (s & 7) == 7) {
                            __threadfence();
                            if (lane == 0) aadd(&hpage[mi * 32 + (s >> 3)], 1u);
                        }
                    }
                    SYNC_LDS();
                }
                {  // final slot Tm-1
                    uint4 h[4];
#pragma unroll
                    for (int c = 0; c < 4; ++c)
                        h[c] = *reinterpret_cast<const uint4*>(
                            smem + (Tm & 1) * 4096 + soff[c]);
                    unsigned short* dst = hm + (size_t)(Tm - 1) * BB * HH;
#pragma unroll
                    for (int c = 0; c < 4; ++c)
                        *reinterpret_cast<uint4*>(dst + c * 8) = h[c];
                    if (mi > 0) {
                        __threadfence();
                        if (lane == 0) aadd(&hpage[mi * 32 + ((Tm - 1) >> 3)], 1u);
                    }
                }
                SYNC_LDS();  // phase end
            }
        }
    } else {
        // ===================== worker block =====================
        for (;;) {
            if (tid == 0)
                s_item = (int)__hip_atomic_fetch_add(counter, 1u, __ATOMIC_RELAXED,
                                                     __HIP_MEMORY_SCOPE_AGENT);
            __syncthreads();
            int i = s_item;
            if (i >= 508) break;
            int mi, k;
            item_of(i, mi, k);
            if (k > 0 && tid == 0) {
                int t = k << mi;
                for (int j = mi + 1; j < 8; ++j) {
                    int pg = ((t - 1) >> j) >> 3;
                    while (aload(&hpage[j * 32 + pg]) < 8u)
                        __builtin_amdgcn_s_sleep(32);
                }
            }
            __syncthreads();
            u_body(mi, k, Whh, hprev, hmod, xwb, smem);
            __threadfence();
            __syncthreads();
            if (tid == 0) aadd(&uflag[mi * 256 + k], 1u);
            __syncthreads();
        }
    }
}

// ---------------------------------------------------------------------------
// K_out (unchanged).
// ---------------------------------------------------------------------------
__global__ __launch_bounds__(256) void k_out(const unsigned short* __restrict__ hmod,
                                             float* __restrict__ out) {
    int b = blockIdx.x, t = blockIdx.y;
    int tid = threadIdx.x;
    int i = tid * 4;
    int j = i >> 7;
    int k = t >> j;
    ushort4 h = *reinterpret_cast<const ushort4*>(
        &hmod[c_hmod_off[j] + ((size_t)k * BB + b) * HH + (i & 127)]);
    float4 v = make_float4(bf2f(h.x), bf2f(h.y), bf2f(h.z), bf2f(h.w));
    *reinterpret_cast<float4*>(&out[((size_t)t * BB + b) * MHW + i]) = v;
    if (t == TT - 1) {
        *reinterpret_cast<float4*>(
            &out[(size_t)TT * BB * MHW + (size_t)b * MHW + i]) = v;
    }
}

// ---------------------------------------------------------------------------
extern "C" void kernel_launch(void* const* d_in, const int* in_sizes, int n_in,
                              void* d_out, int out_size, void* d_ws, size_t ws_size,
                              hipStream_t stream) {
    const float* x = (const float*)d_in[0];
    const float* hprev = (const float*)d_in[1];
    const float* Wxh = (const float*)d_in[2];
    const float* Whh = (const float*)d_in[3];
    const float* bh = (const float*)d_in[4];
    float* out = (float*)d_out;

    float* xwb = out;                                  // scratch in d_out
    unsigned short* hmod = (unsigned short*)d_ws;      // bf16, 16.7 MB
    unsigned int* flags = (unsigned int*)((char*)d_ws + 16711680);

    k_xw<<<dim3(1020), 256, 0, stream>>>(x, Wxh, bh, xwb, flags);
    k_mega<<<dim3(256), 256, 0, stream>>>(Whh, hprev, xwb, hmod, flags);
    k_out<<<dim3(128, 256), 256, 0, stream>>>(hmod, out);
}

// Round 16
// 408.993 us; speedup vs baseline: 1.4277x; 1.2390x over previous
//
#include <hip/hip_runtime.h>
#include <hip/hip_bf16.h>

// Clockwork RNN, hierarchical decomposition + bf16 MFMA GEMMs.
// Round 16: R13 base (best measured, 404 us) + k_phase v10 micro-opts:
//   - sH ring depth 4 (storer gets 3 steps of overwrite slack)
//   - storer unrolled x2 with distinct reg sets (store-retire wait spans 2 steps)
//   - s_setprio(1) on compute waves during the step loop (T5; role-split exists)
// Dataflow identical to verified v6. k_xw / k_u / k_out unchanged from R13.

#define TT 256
#define BB 128
#define INW 512
#define HH 128
#define MHW 1024

typedef __bf16 bf16x8 __attribute__((ext_vector_type(8)));
typedef __bf16 bf16x4 __attribute__((ext_vector_type(4)));
typedef float f32x4 __attribute__((ext_vector_type(4)));

__constant__ unsigned int c_hmod_off[8] = {
    0u, 4194304u, 6291456u, 7340032u, 7864320u, 8126464u, 8257536u, 8323072u};

__device__ __forceinline__ unsigned short f2bf(float f) {
    union { float f; unsigned int u; } v{f};
    unsigned int r = v.u + 0x7FFFu + ((v.u >> 16) & 1u);  // RNE
    return (unsigned short)(r >> 16);
}
__device__ __forceinline__ unsigned int pack2(float lo, float hi) {
    return (unsigned int)f2bf(lo) | ((unsigned int)f2bf(hi) << 16);
}
__device__ __forceinline__ float bf2f(unsigned short u) {
    union { unsigned int i; float f; } v;
    v.i = ((unsigned int)u) << 16;
    return v.f;
}

__device__ __forceinline__ void gld_lds16(const void* g, char* l) {
    __builtin_amdgcn_global_load_lds(
        (const __attribute__((address_space(1))) void*)g,
        (__attribute__((address_space(3))) void*)l, 16, 0, 0);
}

// Read one 16x32 bf16 fragment (8 bf16) from a swizzled bf16 tile.
__device__ __forceinline__ bf16x8 frag_ld(const char* tile, int row, int ks, int lane) {
    int off = (row * 128 + ks * 64 + (lane >> 4) * 16) ^ ((row & 7) << 4);
    return *reinterpret_cast<const bf16x8*>(tile + off);
}

// Read one fragment from a swizzled *f32* tile ([rows][64] f32, 256B/row),
// convert to bf16x8 (compiler emits packed cvt).
__device__ __forceinline__ bf16x8 frag_ld_f32(const char* tile, int row, int ks, int g) {
    int off = ((row << 8) + ks * 128 + g * 32) ^ ((row & 7) << 4);
    f32x4 a = *reinterpret_cast<const f32x4*>(tile + off);
    f32x4 b = *reinterpret_cast<const f32x4*>(tile + (off ^ 16));
    bf16x8 u;
    u[0] = (__bf16)a[0]; u[1] = (__bf16)a[1]; u[2] = (__bf16)a[2]; u[3] = (__bf16)a[3];
    u[4] = (__bf16)b[0]; u[5] = (__bf16)b[1]; u[6] = (__bf16)b[2]; u[7] = (__bf16)b[3];
    return u;
}

// ---------------------------------------------------------------------------
// K_xw (unchanged R13): 1020 uniform blocks, gld_lds f32 staging.
// ---------------------------------------------------------------------------
__global__ __launch_bounds__(256) void k_xw(const float* __restrict__ x,
                                            const float* __restrict__ Wxh,
                                            const float* __restrict__ bh,
                                            float* __restrict__ xwb) {
    __shared__ char ldsW[2][32768];
    __shared__ char ldsX[2][16384];
    int id = blockIdx.x >> 1, half = blockIdx.x & 1;
    int rt = 0, rem = id;
    while (rem >= (256 >> rt)) { rem -= 256 >> rt; ++rt; }
    int t = rem << rt;

    int tid = threadIdx.x, lane = tid & 63, wid = tid >> 6;
    int l15 = lane & 15, g = lane >> 4;
    int wr = (wid >> 1) * 64, wc = (wid & 1) * 32;

    const float* gW[8];
    const float* gX[4];
    {
        int kb = (lane & 15) * 16;
#pragma unroll
        for (int i = 0; i < 8; ++i) {
            int row = i * 16 + wid * 4 + (lane >> 4);
            int kf = (kb ^ ((row & 7) << 4)) >> 2;
            gW[i] = Wxh + (size_t)(rt * 128 + row) * INW + kf;
        }
#pragma unroll
        for (int i = 0; i < 4; ++i) {
            int row = i * 16 + wid * 4 + (lane >> 4);
            int kf = (kb ^ ((row & 7) << 4)) >> 2;
            gX[i] = x + ((size_t)t * BB + half * 64 + row) * INW + kf;
        }
    }
#pragma unroll
    for (int i = 0; i < 8; ++i)
        gld_lds16(gW[i], &ldsW[0][0] + i * 4096 + wid * 1024);
#pragma unroll
    for (int i = 0; i < 4; ++i)
        gld_lds16(gX[i], &ldsX[0][0] + i * 4096 + wid * 1024);

    f32x4 acc[4][2] = {};
    for (int c = 0; c < 8; ++c) {
        int cur = c & 1;
        __syncthreads();
        if (c < 7) {
#pragma unroll
            for (int i = 0; i < 8; ++i)
                gld_lds16(gW[i] + (c + 1) * 64,
                          &ldsW[cur ^ 1][0] + i * 4096 + wid * 1024);
#pragma unroll
            for (int i = 0; i < 4; ++i)
                gld_lds16(gX[i] + (c + 1) * 64,
                          &ldsX[cur ^ 1][0] + i * 4096 + wid * 1024);
        }
#pragma unroll
        for (int ks = 0; ks < 2; ++ks) {
            bf16x8 fa[4], fb[2];
#pragma unroll
            for (int i = 0; i < 4; ++i)
                fa[i] = frag_ld_f32(&ldsW[cur][0], wr + i * 16 + l15, ks, g);
#pragma unroll
            for (int j = 0; j < 2; ++j)
                fb[j] = frag_ld_f32(&ldsX[cur][0], wc + j * 16 + l15, ks, g);
#pragma unroll
            for (int i = 0; i < 4; ++i)
#pragma unroll
                for (int j = 0; j < 2; ++j)
                    acc[i][j] = __builtin_amdgcn_mfma_f32_16x16x32_bf16(
                        fa[i], fb[j], acc[i][j], 0, 0, 0);
        }
    }
#pragma unroll
    for (int i = 0; i < 4; ++i) {
        int rbase = rt * 128 + wr + i * 16 + g * 4;
        float4 bias = *reinterpret_cast<const float4*>(&bh[rbase]);
#pragma unroll
        for (int j = 0; j < 2; ++j) {
            int b = half * 64 + wc + j * 16 + l15;
            float4 v = make_float4(acc[i][j][0] + bias.x, acc[i][j][1] + bias.y,
                                   acc[i][j][2] + bias.z, acc[i][j][3] + bias.w);
            *reinterpret_cast<float4*>(
                &xwb[(size_t)(t * BB + b) * MHW + rbase]) = v;
        }
    }
}

// ---------------------------------------------------------------------------
// K_u (unchanged R13): gld_lds staging for A (f32) and H (hprev f32 / hmod bf16).
// ---------------------------------------------------------------------------
__global__ __launch_bounds__(256) void k_u(const float* __restrict__ Whh,
                                           const float* __restrict__ hprev,
                                           const unsigned short* __restrict__ hmod,
                                           float* __restrict__ xwb, int mi) {
    __shared__ char lds[131072];
    char* ldsA0 = lds;
    char* ldsA1 = lds + 32768;
    char* ldsH0 = lds + 65536;
    char* ldsH1 = lds + 98304;
    int k = blockIdx.x;
    int t = k << mi;
    int tid = threadIdx.x, lane = tid & 63, wid = tid >> 6;
    int l15 = lane & 15, g = lane >> 4;
    int wr = (wid >> 1) * 64, wc = (wid & 1) * 64;
    int ntile = 2 * (7 - mi);

    const float* gA[8];
    {
        int kb = l15 * 16;
#pragma unroll
        for (int i = 0; i < 8; ++i) {
            int row = i * 16 + wid * 4 + g;
            int kf = (kb ^ ((row & 7) << 4)) >> 2;
            gA[i] = Whh + (size_t)(mi * HH + row) * MHW + kf;
        }
    }
    f32x4 acc[4][4] = {};

    if (k == 0) {
        const float* gH[8];
        {
            int kb = l15 * 16;
#pragma unroll
            for (int i = 0; i < 8; ++i) {
                int row = i * 16 + wid * 4 + g;
                int kf = (kb ^ ((row & 7) << 4)) >> 2;
                gH[i] = hprev + (size_t)row * MHW + kf;
            }
        }
        auto stage = [&](int tt, char* dA, char* dH) {
            int j = mi + 1 + (tt >> 1), c0 = (tt & 1) * 64;
            int off = j * HH + c0;
#pragma unroll
            for (int i = 0; i < 8; ++i)
                gld_lds16(gA[i] + off, dA + i * 4096 + wid * 1024);
#pragma unroll
            for (int i = 0; i < 8; ++i)
                gld_lds16(gH[i] + off, dH + i * 4096 + wid * 1024);
        };
        stage(0, ldsA0, ldsH0);
        for (int tt = 0; tt < ntile; ++tt) {
            int cur = tt & 1;
            __syncthreads();
            if (tt + 1 < ntile)
                stage(tt + 1, cur ? ldsA0 : ldsA1, cur ? ldsH0 : ldsH1);
            const char* sA = cur ? ldsA1 : ldsA0;
            const char* sH = cur ? ldsH1 : ldsH0;
#pragma unroll
            for (int ks = 0; ks < 2; ++ks) {
                bf16x8 fa[4], fb[4];
#pragma unroll
                for (int i = 0; i < 4; ++i) {
                    fa[i] = frag_ld_f32(sA, wr + i * 16 + l15, ks, g);
                    fb[i] = frag_ld_f32(sH, wc + i * 16 + l15, ks, g);
                }
#pragma unroll
                for (int i = 0; i < 4; ++i)
#pragma unroll
                    for (int jj = 0; jj < 4; ++jj)
                        acc[i][jj] = __builtin_amdgcn_mfma_f32_16x16x32_bf16(
                            fa[i], fb[jj], acc[i][jj], 0, 0, 0);
            }
        }
    } else {
        size_t hoff[4];
        {
            int cb = ((lane & 7) * 16) ^ ((lane >> 3) << 4);
#pragma unroll
            for (int p = 0; p < 4; ++p) {
                int row = p * 32 + wid * 8 + (lane >> 3);
                hoff[p] = (size_t)row * HH + (cb >> 1);
            }
        }
        auto stage = [&](int tt, char* dA, char* dH) {
            int j = mi + 1 + (tt >> 1), c0 = (tt & 1) * 64;
            int offA = j * HH + c0;
#pragma unroll
            for (int i = 0; i < 8; ++i)
                gld_lds16(gA[i] + offA, dA + i * 4096 + wid * 1024);
            const unsigned short* hb =
                hmod + c_hmod_off[j] + (size_t)((t - 1) >> j) * BB * HH + c0;
#pragma unroll
            for (int p = 0; p < 4; ++p)
                gld_lds16(hb + hoff[p], dH + p * 4096 + wid * 1024);
        };
        stage(0, ldsA0, ldsH0);
        for (int tt = 0; tt < ntile; ++tt) {
            int cur = tt & 1;
            __syncthreads();
            if (tt + 1 < ntile)
                stage(tt + 1, cur ? ldsA0 : ldsA1, cur ? ldsH0 : ldsH1);
            const char* sA = cur ? ldsA1 : ldsA0;
            const char* sH = cur ? ldsH1 : ldsH0;
#pragma unroll
            for (int ks = 0; ks < 2; ++ks) {
                bf16x8 fa[4], fb[4];
#pragma unroll
                for (int i = 0; i < 4; ++i) {
                    fa[i] = frag_ld_f32(sA, wr + i * 16 + l15, ks, g);
                    fb[i] = frag_ld(sH, wc + i * 16 + l15, ks, lane);
                }
#pragma unroll
                for (int i = 0; i < 4; ++i)
#pragma unroll
                    for (int jj = 0; jj < 4; ++jj)
                        acc[i][jj] = __builtin_amdgcn_mfma_f32_16x16x32_bf16(
                            fa[i], fb[jj], acc[i][jj], 0, 0, 0);
            }
        }
    }
#pragma unroll
    for (int i = 0; i < 4; ++i) {
        int rbase = wr + i * 16 + g * 4;
#pragma unroll
        for (int j = 0; j < 4; ++j) {
            int b = wc + j * 16 + l15;
            float4* p = reinterpret_cast<float4*>(
                &xwb[(size_t)(t * BB + b) * MHW + mi * HH + rbase]);
            float4 v = *p;
            v.x += acc[i][j][0]; v.y += acc[i][j][1];
            v.z += acc[i][j][2]; v.w += acc[i][j][3];
            *p = v;
        }
    }
}

// ---------------------------------------------------------------------------
// K_phase v10: v6 dataflow + ring4 + storer unroll2 + compute setprio.
// grid 8 blocks x 16 batches, 256 thr = waves {0,1}: compute, 2: u-producer,
// 3: h-storer.
// ---------------------------------------------------------------------------
#define SYNC_LDS()                                              \
    do {                                                        \
        asm volatile("s_waitcnt lgkmcnt(0)" ::: "memory");      \
        __builtin_amdgcn_sched_barrier(0);                      \
        __builtin_amdgcn_s_barrier();                           \
        __builtin_amdgcn_sched_barrier(0);                      \
    } while (0)
#define SYNC_VM24()                                             \
    do {                                                        \
        asm volatile("s_waitcnt vmcnt(24)" ::: "memory");       \
        __builtin_amdgcn_sched_barrier(0);                      \
        __builtin_amdgcn_s_barrier();                           \
        __builtin_amdgcn_sched_barrier(0);                      \
    } while (0)

__global__ __launch_bounds__(256) void k_phase(const float* __restrict__ Whh,
                                               const float* __restrict__ hprev,
                                               const float* __restrict__ xwb,
                                               unsigned short* __restrict__ hmod,
                                               int mi) {
    int b0 = blockIdx.x * 16;
    int tid = threadIdx.x, lane = tid & 63, wid = tid >> 6;
    int l15 = lane & 15, g = lane >> 4;
    __shared__ char sH[4][4096];   // h ring: slot K&3 = h_K, [b][r] bf16 swizzled
    __shared__ char sU[8][8192];   // u ring: slot K&7, [r/4][b][4xf32], linear
    int Tm = TT >> mi;

    if (wid < 2) {
        // ================= compute waves =================
        bf16x8 Af[4][4];
        {
            const float* Ab = Whh + (size_t)(mi * HH) * MHW + mi * HH;
#pragma unroll
            for (int mm = 0; mm < 4; ++mm) {
                const float* row = Ab + (size_t)(64 * wid + mm * 16 + l15) * MHW;
#pragma unroll
                for (int kf = 0; kf < 4; ++kf) {
                    float4 v0 = *reinterpret_cast<const float4*>(row + kf * 32 + g * 8);
                    float4 v1 = *reinterpret_cast<const float4*>(row + kf * 32 + g * 8 + 4);
                    bf16x8 u;
                    u[0] = (__bf16)v0.x; u[1] = (__bf16)v0.y;
                    u[2] = (__bf16)v0.z; u[3] = (__bf16)v0.w;
                    u[4] = (__bf16)v1.x; u[5] = (__bf16)v1.y;
                    u[6] = (__bf16)v1.z; u[7] = (__bf16)v1.w;
                    Af[mm][kf] = u;
                }
            }
        }
        // initial H (h_{-1}) into ring slot 3 (step 0 reads (0+3)&3 = 3)
#pragma unroll
        for (int p = 0; p < 2; ++p) {
            int tt = tid + p * 128;
            int b = tt >> 4, r8 = (tt & 15) * 8;
            const float* hp = hprev + (size_t)(b0 + b) * MHW + mi * HH + r8;
            float4 v0 = *reinterpret_cast<const float4*>(hp);
            float4 v1 = *reinterpret_cast<const float4*>(hp + 4);
            uint4 pk;
            pk.x = pack2(v0.x, v0.y); pk.y = pack2(v0.z, v0.w);
            pk.z = pack2(v1.x, v1.y); pk.w = pack2(v1.z, v1.w);
            int off = (b * 256 + r8 * 2) ^ ((b & 7) << 4);
            *reinterpret_cast<uint4*>(&sH[3][0] + off) = pk;
        }
        int roff[4], woff[4], uoff[4];
#pragma unroll
        for (int kf = 0; kf < 4; ++kf)
            roff[kf] = (l15 * 256 + kf * 64 + g * 16) ^ ((l15 & 7) << 4);
#pragma unroll
        for (int mm = 0; mm < 4; ++mm) {
            woff[mm] = (l15 * 256 + (64 * wid + mm * 16 + g * 4) * 2) ^ ((l15 & 7) << 4);
            uoff[mm] = (16 * wid + 4 * mm + g) * 256 + l15 * 16;
        }
        SYNC_LDS();

        __builtin_amdgcn_s_setprio(1);
        for (int K = 0; K < Tm; ++K) {
            const char* hin = &sH[(K + 3) & 3][0];
            char* hout = &sH[K & 3][0];
            const char* ub = &sU[K & 7][0];
            f32x4 acc[4], acc2[4];
#pragma unroll
            for (int mm = 0; mm < 4; ++mm) {
                acc[mm] = *reinterpret_cast<const f32x4*>(ub + uoff[mm]);
                acc2[mm] = (f32x4){0.f, 0.f, 0.f, 0.f};
            }
            bf16x8 Bf[4];
#pragma unroll
            for (int kf = 0; kf < 4; ++kf)
                Bf[kf] = *reinterpret_cast<const bf16x8*>(hin + roff[kf]);
#pragma unroll
            for (int mm = 0; mm < 4; ++mm) {
                acc[mm] = __builtin_amdgcn_mfma_f32_16x16x32_bf16(
                    Af[mm][0], Bf[0], acc[mm], 0, 0, 0);
                acc2[mm] = __builtin_amdgcn_mfma_f32_16x16x32_bf16(
                    Af[mm][2], Bf[2], acc2[mm], 0, 0, 0);
                acc[mm] = __builtin_amdgcn_mfma_f32_16x16x32_bf16(
                    Af[mm][1], Bf[1], acc[mm], 0, 0, 0);
                acc2[mm] = __builtin_amdgcn_mfma_f32_16x16x32_bf16(
                    Af[mm][3], Bf[3], acc2[mm], 0, 0, 0);
            }
#pragma unroll
            for (int mm = 0; mm < 4; ++mm) {
                acc[mm] += acc2[mm];
                bf16x4 pk;
                pk[0] = (__bf16)acc[mm][0]; pk[1] = (__bf16)acc[mm][1];
                pk[2] = (__bf16)acc[mm][2]; pk[3] = (__bf16)acc[mm][3];
                *reinterpret_cast<bf16x4*>(hout + woff[mm]) = pk;
            }
            SYNC_LDS();
        }
        __builtin_amdgcn_s_setprio(0);
    } else if (wid == 2) {
        // ================= u producer (unchanged v6) =================
        const float* ubase = xwb + (size_t)(b0 + l15) * MHW + mi * HH + g * 4;
#pragma unroll
        for (int q = 0; q < 4; ++q) {  // prologue: slots 0..3
            int t = min(q, Tm - 1) << mi;
            const float* pt = ubase + (size_t)t * BB * MHW;
#pragma unroll
            for (int p = 0; p < 8; ++p)
                gld_lds16(pt + p * 16, &sU[q][0] + p * 1024);
        }
        SYNC_VM24();  // retires slot 0
        for (int K = 0; K < Tm; ++K) {
            int t = min(K + 4, Tm - 1) << mi;
            int slot = (K + 4) & 7;
            const float* pt = ubase + (size_t)t * BB * MHW;
#pragma unroll
            for (int p = 0; p < 8; ++p)
                gld_lds16(pt + p * 16, &sU[slot][0] + p * 1024);
            SYNC_VM24();  // retires slot K+1 (needed next step)
        }
        asm volatile("s_waitcnt vmcnt(0)" ::: "memory");
    } else {
        // ================= h storer (unroll x2, distinct reg sets) =========
        int bq = lane >> 2;
        int rr = (lane & 3) * 32;
        unsigned short* hm =
            hmod + c_hmod_off[mi] + (size_t)(b0 + bq) * HH + rr;
        int soff[4];
#pragma unroll
        for (int c = 0; c < 4; ++c)
            soff[c] = (bq * 256 + (rr + c * 8) * 2) ^ ((bq & 7) << 4);
        SYNC_LDS();
        // Tm is a power of two >= 2, so the pair loop covers all K.
        for (int K = 0; K + 1 < Tm; K += 2) {
            // iter K: store h_{K-1} from slot (K-1)&3 (skip at K==0)
            if (K >= 1) {
                uint4 ha[4];
#pragma unroll
                for (int c = 0; c < 4; ++c)
                    ha[c] = *reinterpret_cast<const uint4*>(
                        &sH[(K - 1) & 3][0] + soff[c]);
                unsigned short* dst = hm + (size_t)(K - 1) * BB * HH;
#pragma unroll
                for (int c = 0; c < 4; ++c)
                    *reinterpret_cast<uint4*>(dst + c * 8) = ha[c];
            }
            SYNC_LDS();
            // iter K+1: store h_K from slot K&3
            {
                uint4 hb[4];
#pragma unroll
                for (int c = 0; c < 4; ++c)
                    hb[c] = *reinterpret_cast<const uint4*>(
                        &sH[K & 3][0] + soff[c]);
                unsigned short* dst = hm + (size_t)K * BB * HH;
#pragma unroll
                for (int c = 0; c < 4; ++c)
                    *reinterpret_cast<uint4*>(dst + c * 8) = hb[c];
            }
            SYNC_LDS();
        }
        {  // final: h_{Tm-1} from slot (Tm-1)&3
            uint4 h[4];
#pragma unroll
            for (int c = 0; c < 4; ++c)
                h[c] = *reinterpret_cast<const uint4*>(
                    &sH[(Tm - 1) & 3][0] + soff[c]);
            unsigned short* dst = hm + (size_t)(Tm - 1) * BB * HH;
#pragma unroll
            for (int c = 0; c < 4; ++c)
                *reinterpret_cast<uint4*>(dst + c * 8) = h[c];
        }
    }
}

// ---------------------------------------------------------------------------
// K_out (unchanged): out[t][b][j*H + h] = bf2f(Hmod[j][t>>j][b][h]); h_last.
// ---------------------------------------------------------------------------
__global__ __launch_bounds__(256) void k_out(const unsigned short* __restrict__ hmod,
                                             float* __restrict__ out) {
    int b = blockIdx.x, t = blockIdx.y;
    int tid = threadIdx.x;
    int i = tid * 4;
    int j = i >> 7;
    int k = t >> j;
    ushort4 h = *reinterpret_cast<const ushort4*>(
        &hmod[c_hmod_off[j] + ((size_t)k * BB + b) * HH + (i & 127)]);
    float4 v = make_float4(bf2f(h.x), bf2f(h.y), bf2f(h.z), bf2f(h.w));
    *reinterpret_cast<float4*>(&out[((size_t)t * BB + b) * MHW + i]) = v;
    if (t == TT - 1) {
        *reinterpret_cast<float4*>(
            &out[(size_t)TT * BB * MHW + (size_t)b * MHW + i]) = v;
    }
}

// ---------------------------------------------------------------------------
extern "C" void kernel_launch(void* const* d_in, const int* in_sizes, int n_in,
                              void* d_out, int out_size, void* d_ws, size_t ws_size,
                              hipStream_t stream) {
    const float* x = (const float*)d_in[0];
    const float* hprev = (const float*)d_in[1];
    const float* Wxh = (const float*)d_in[2];
    const float* Whh = (const float*)d_in[3];
    const float* bh = (const float*)d_in[4];
    float* out = (float*)d_out;

    float* xwb = out;                              // scratch in d_out
    unsigned short* hmod = (unsigned short*)d_ws;  // bf16, 16.7 MB

    k_xw<<<dim3(1020), 256, 0, stream>>>(x, Wxh, bh, xwb);

    for (int mi = 7; mi >= 0; --mi) {
        if (mi < 7)
            k_u<<<dim3(TT >> mi), 256, 0, stream>>>(Whh, hprev, hmod, xwb, mi);
        k_phase<<<8, 256, 0, stream>>>(Whh, hprev, xwb, hmod, mi);
    }

    k_out<<<dim3(128, 256), 256, 0, stream>>>(hmod, out);
}